// Round 1
// baseline (360.736 us; speedup 1.0000x reference)
//
#include <hip/hip_runtime.h>

// RankingLoss on MI355X.
// inputs: out1 [8192,128] f32, out2 [8192,128] f32, anchor1 [512] i32, anchor2 [512] i32
// output: scalar f32 loss.
//
// Pipeline (workspace path):
//   dist_kernel: D[1024][8192] f32 distance matrix (rows 0..511: a1 vs out2,
//                rows 512..1023: a2 vs out1), tiled 128x128 per block, 8x8 reg tile.
//   select_kernel: per row, exact 32nd-smallest via bitwise radix search on f32
//                bit patterns (non-negative floats are order-isomorphic to uint),
//                then sum relu(D - d) over the 32 smallest with exact tie handling.
// Fallback (ws too small): fused per-row kernel (slower but exact).

#define NN 8192      // nodes
#define DF 128       // feature dim
#define NA 512       // anchors
#define KK 32        // negatives per anchor
#define VPT 32       // values per thread in select (NN / 256)

// ---------------- reductions ----------------

__device__ __forceinline__ float wave_reduce_f(float x) {
#pragma unroll
  for (int off = 32; off > 0; off >>= 1) x += __shfl_down(x, off);
  return x;
}

__device__ __forceinline__ int wave_reduce_i(int x) {
#pragma unroll
  for (int off = 32; off > 0; off >>= 1) x += __shfl_down(x, off);
  return x;
}

// D = L1(out1[anchor1[a]], out2[anchor2[a]]) + MARGIN, block-wide (blockDim=256)
__device__ __forceinline__ float compute_D(const float* __restrict__ out1,
                                           const float* __restrict__ out2,
                                           const int* __restrict__ anchor1,
                                           const int* __restrict__ anchor2,
                                           int a) {
  __shared__ float dred[4];
  const int tid = threadIdx.x;
  float p = 0.f;
  if (tid < DF) {
    const int r1 = anchor1[a];
    const int r2 = anchor2[a];
    p = fabsf(out1[(size_t)r1 * DF + tid] - out2[(size_t)r2 * DF + tid]);
  }
  p = wave_reduce_f(p);
  const int lane = tid & 63, wid = tid >> 6;
  if (lane == 0) dred[wid] = p;
  __syncthreads();
  return dred[0] + dred[1] + dred[2] + dred[3] + 1.0f;  // MARGIN = 1.0
}

// Exact top-32 ranking-loss partial for one row; u[] = per-thread 32 distance
// bit-patterns (any partition of the 8192 values). Accumulates into *out.
__device__ __forceinline__ void select_accum(const unsigned* u, float Dv,
                                             float* __restrict__ out) {
  __shared__ int redi[4];
  __shared__ float redf[4];
  const int tid = threadIdx.x;
  const int lane = tid & 63, wid = tid >> 6;

  // Bitwise binary search for T = 32nd smallest (bit 31 is 0: distances >= 0).
  unsigned P = 0;
  for (int b = 30; b >= 0; --b) {
    const unsigned mid = P | (1u << b);
    int c = 0;
#pragma unroll
    for (int i = 0; i < VPT; ++i) c += (u[i] < mid) ? 1 : 0;
    c = wave_reduce_i(c);
    __syncthreads();  // redi safe to overwrite (readers of prev iter done)
    if (lane == 0) redi[wid] = c;
    __syncthreads();
    const int tot = redi[0] + redi[1] + redi[2] + redi[3];
    if (tot < KK) P = mid;  // uniform across block
  }

  // Sum relu(D - d) over d < T, count them; ties at T handled analytically.
  float s = 0.f;
  int c = 0;
#pragma unroll
  for (int i = 0; i < VPT; ++i) {
    if (u[i] < P) {
      const float t = Dv - __uint_as_float(u[i]);
      s += (t > 0.f) ? t : 0.f;
      c += 1;
    }
  }
  s = wave_reduce_f(s);
  c = wave_reduce_i(c);
  __syncthreads();
  if (lane == 0) {
    redf[wid] = s;
    redi[wid] = c;
  }
  __syncthreads();
  if (tid == 0) {
    float stot = redf[0] + redf[1] + redf[2] + redf[3];
    const int ctot = redi[0] + redi[1] + redi[2] + redi[3];
    float tt = Dv - __uint_as_float(P);
    if (tt < 0.f) tt = 0.f;
    stot += (float)(KK - ctot) * tt;
    atomicAdd(out, stot * (1.0f / (float)(NA * KK)));
  }
}

// ---------------- kernel 1: distance matrix ----------------
// grid: (64 node tiles, 4 anchor tiles, 2 dirs), block 256.
// Tile: 128 nodes x 128 anchors, dims chunked by 32 through LDS, 8x8 reg tile.

__global__ __launch_bounds__(256, 2) void dist_kernel(
    const float* __restrict__ out1, const float* __restrict__ out2,
    const int* __restrict__ anchor1, const int* __restrict__ anchor2,
    float* __restrict__ dist) {
  const int tid = threadIdx.x;
  const int nb = blockIdx.x;   // node tile
  const int ab = blockIdx.y;   // anchor tile
  const int dir = blockIdx.z;  // 0: a1 vs out2, 1: a2 vs out1
  const float* nodes = dir ? out1 : out2;
  const float* asrc = dir ? out2 : out1;
  const int* aidx = dir ? anchor2 : anchor1;
  const int n0 = nb * 128;
  const int a0 = ab * 128;

  __shared__ float nds[128][36];  // node rows, 32-dim chunk + pad
  __shared__ float ads[128][36];  // anchor rows

  float acc[8][8];
#pragma unroll
  for (int i = 0; i < 8; ++i)
#pragma unroll
    for (int j = 0; j < 8; ++j) acc[i][j] = 0.f;

  const int tn = tid & 15;   // node group
  const int ta = tid >> 4;   // anchor group

  for (int cch = 0; cch < 4; ++cch) {
    const int d0 = cch * 32;
    __syncthreads();  // previous chunk's readers done before overwrite
#pragma unroll
    for (int r = 0; r < 4; ++r) {
      const int f = tid + 256 * r;  // 0..1023 float4 slots
      const int row = f >> 3;       // 0..127
      const int c4 = f & 7;         // 0..7
      const float4 nv =
          *(const float4*)(nodes + (size_t)(n0 + row) * DF + d0 + c4 * 4);
      *(float4*)&nds[row][c4 * 4] = nv;
      const int ar = aidx[a0 + row];
      const float4 av =
          *(const float4*)(asrc + (size_t)ar * DF + d0 + c4 * 4);
      *(float4*)&ads[row][c4 * 4] = av;
    }
    __syncthreads();
#pragma unroll
    for (int d4 = 0; d4 < 8; ++d4) {
      float4 nv[8], av[8];
#pragma unroll
      for (int i = 0; i < 8; ++i) nv[i] = *(const float4*)&nds[tn + 16 * i][d4 * 4];
#pragma unroll
      for (int j = 0; j < 8; ++j) av[j] = *(const float4*)&ads[ta + 16 * j][d4 * 4];
#pragma unroll
      for (int i = 0; i < 8; ++i)
#pragma unroll
        for (int j = 0; j < 8; ++j) {
          acc[i][j] += fabsf(nv[i].x - av[j].x);
          acc[i][j] += fabsf(nv[i].y - av[j].y);
          acc[i][j] += fabsf(nv[i].z - av[j].z);
          acc[i][j] += fabsf(nv[i].w - av[j].w);
        }
    }
  }

  const size_t rowbase = (size_t)(dir * NA + a0) * NN;
#pragma unroll
  for (int j = 0; j < 8; ++j) {
#pragma unroll
    for (int i = 0; i < 8; ++i) {
      dist[rowbase + (size_t)(ta + 16 * j) * NN + n0 + tn + 16 * i] = acc[i][j];
    }
  }
}

// ---------------- kernel 2: selection + loss ----------------
// grid: 1024 blocks (one per (dir, anchor)), block 256.

__global__ __launch_bounds__(256) void select_kernel(
    const float* __restrict__ dist, const float* __restrict__ out1,
    const float* __restrict__ out2, const int* __restrict__ anchor1,
    const int* __restrict__ anchor2, float* __restrict__ out) {
  const int tid = threadIdx.x;
  const int row = blockIdx.x;  // 0..1023
  const int a = row & (NA - 1);

  unsigned u[VPT];
  const float4* drow = (const float4*)(dist + (size_t)row * NN);
#pragma unroll
  for (int g = 0; g < 8; ++g) {
    const float4 t = drow[tid + 256 * g];
    u[4 * g + 0] = __float_as_uint(t.x);
    u[4 * g + 1] = __float_as_uint(t.y);
    u[4 * g + 2] = __float_as_uint(t.z);
    u[4 * g + 3] = __float_as_uint(t.w);
  }

  const float Dv = compute_D(out1, out2, anchor1, anchor2, a);
  select_accum(u, Dv, out);
}

// ---------------- fallback: fused (no workspace) ----------------

__global__ __launch_bounds__(256) void fused_kernel(
    const float* __restrict__ out1, const float* __restrict__ out2,
    const int* __restrict__ anchor1, const int* __restrict__ anchor2,
    float* __restrict__ out) {
  const int tid = threadIdx.x;
  const int row = blockIdx.x;  // 0..1023
  const int dir = row >> 9;
  const int a = row & (NA - 1);
  const float* nodes = dir ? out1 : out2;
  const float* asrc = dir ? out2 : out1;
  const int* aidx = dir ? anchor2 : anchor1;

  __shared__ float ars[DF];
  if (tid < DF / 4) {
    const int arow = aidx[a];
    const float4 t = *(const float4*)(asrc + (size_t)arow * DF + tid * 4);
    *(float4*)&ars[tid * 4] = t;
  }
  __syncthreads();

  unsigned u[VPT];
  for (int i = 0; i < VPT; ++i) {
    const int n = tid + 256 * i;
    const float4* nrow = (const float4*)(nodes + (size_t)n * DF);
    float dsum = 0.f;
    for (int d4 = 0; d4 < DF / 4; ++d4) {
      const float4 t = nrow[d4];
      const float4 av = *(const float4*)&ars[d4 * 4];
      dsum += fabsf(t.x - av.x) + fabsf(t.y - av.y) + fabsf(t.z - av.z) +
              fabsf(t.w - av.w);
    }
    u[i] = __float_as_uint(dsum);
  }
  __syncthreads();

  const float Dv = compute_D(out1, out2, anchor1, anchor2, a);
  select_accum(u, Dv, out);
}

// ---------------- launch ----------------

extern "C" void kernel_launch(void* const* d_in, const int* in_sizes, int n_in,
                              void* d_out, int out_size, void* d_ws,
                              size_t ws_size, hipStream_t stream) {
  const float* out1 = (const float*)d_in[0];
  const float* out2 = (const float*)d_in[1];
  const int* anchor1 = (const int*)d_in[2];
  const int* anchor2 = (const int*)d_in[3];
  float* out = (float*)d_out;

  hipMemsetAsync(d_out, 0, sizeof(float), stream);

  const size_t need = (size_t)2 * NA * NN * sizeof(float);  // 32 MB
  if (ws_size >= need) {
    float* dist = (float*)d_ws;
    dim3 g1(NN / 128, NA / 128, 2);
    dist_kernel<<<g1, 256, 0, stream>>>(out1, out2, anchor1, anchor2, dist);
    select_kernel<<<2 * NA, 256, 0, stream>>>(dist, out1, out2, anchor1,
                                              anchor2, out);
  } else {
    fused_kernel<<<2 * NA, 256, 0, stream>>>(out1, out2, anchor1, anchor2, out);
  }
}